// Round 3
// baseline (536.605 us; speedup 1.0000x reference)
//
#include <hip/hip_runtime.h>

// Problem constants (from reference)
#define NCH   52            // NC
#define NSs   128           // NS (scan length)
#define NRAYS 64
#define INNER 64            // NR*NT = 4*16; one wave covers one (ray, ch) slab
#define XS    (3*NCH*INNER) // per-s stride in x       = 9984 floats
#define ZS    (2*NCH*INNER) // per-s stride in z_vals  = 6656 floats
#define NOUT  (NRAYS*NCH*INNER)  // 212992 complex outputs

// One thread per output chain: tid = ((r*NC + c)*NR + nr)*NT + nt.
// Inner 6 bits of tid are (nr,nt) -> consecutive lanes read consecutive
// addresses (256 B / wave / load, perfectly coalesced).
//
// Recurrence (reference semantics, verified):
//   f[t]   = (1-alpha[t]) * e^{-i*w*(z[t+1]-z[t])} + 1e-10   (real-part add)
//   P[s]   = prod_{t<s} f[t],  P[0] = 0  (exclusive cumprod, slot0 forced 0)
//   out    = sum_s ch[s] * (ampc/z[s]) * alpha[s] * P[s]
//
// Output layout: PLANAR float32 — [all 212992 reals][all 212992 imags]
// (harness float-view of the complex64 reference, stack(real, imag) axis=0).
__global__ __launch_bounds__(256) void render_kernel(
    const float* __restrict__ x,
    const float* __restrict__ zv,
    const float* __restrict__ fc,
    float* __restrict__ out)
{
    const int tid   = blockIdx.x * blockDim.x + threadIdx.x;   // grid is exact
    const int inner = tid & (INNER - 1);
    const int rc    = tid >> 6;
    const int c     = rc % NCH;
    const int r     = rc / NCH;

    const float* xp = x  + (size_t)r * NSs * XS + c * INNER + inner;
    const float* zp = zv + (size_t)r * NSs * ZS + c * INNER + inner;

    const double C_L    = 299792458.0;
    const double PI_D   = 3.14159265358979323846;
    const float  TWOPI  = 6.28318530717958647692f;
    const float  fcd    = fc[NCH + c];
    // revolutions per unit distance: (2*pi*fc*1e9/C)/(2*pi) = fc*1e9/C
    const double fc_rev = (double)fcd * 1.0e9 / C_L;
    const float  ampc   = (float)(C_L / ((double)fcd * 1.0e9 * 4.0 * PI_D));

    // ---- s = 0: coeffs[0] = alpha[0] * 0 -> no contribution. Build f[0].
    float z_cur  = zp[0];
    float z_next = zp[ZS];
    float ar0    = xp[2 * NCH * INNER];
    float alpha0 = 1.0f - __expf(-ar0);

    double u0 = fc_rev * (double)(z_next - z_cur);
    u0 -= floor(u0);                       // fractional revolutions in [0,1)
    float sn0, cs0;
    __sincosf(TWOPI * (float)u0, &sn0, &cs0);
    float oma0 = 1.0f - alpha0;
    float Pre = oma0 * cs0 + 1e-10f;       // f = (1-alpha)*e^{-i theta} + 1e-10
    float Pim = -oma0 * sn0;               // (+1e-10 on real part only)
    z_cur = z_next;

    float accre = 0.0f, accim = 0.0f;

#pragma unroll 4
    for (int s = 1; s < NSs - 1; ++s) {
        float xre = xp[(size_t)s * XS];
        float xim = xp[(size_t)s * XS + NCH * INNER];
        float ar  = xp[(size_t)s * XS + 2 * NCH * INNER];
        float zn  = zp[(size_t)(s + 1) * ZS];

        float alpha = 1.0f - __expf(-ar);

        // contribution: ch * amp_decay * (alpha * P)
        float amp = ampc / z_cur;          // amp_decay[s] = ampc / z[s]
        float k   = alpha * amp;
        float cre = k * Pre;
        float cim = k * Pim;
        accre = fmaf(xre, cre, fmaf(-xim, cim, accre));
        accim = fmaf(xre, cim, fmaf( xim, cre, accim));

        // update P with f[s]
        double u = fc_rev * (double)(zn - z_cur);
        u -= floor(u);
        float sn, cs;
        __sincosf(TWOPI * (float)u, &sn, &cs);
        float oma = 1.0f - alpha;
        float fre = oma * cs + 1e-10f;
        float fim = -oma * sn;
        float nre = Pre * fre - Pim * fim;
        float nim = Pre * fim + Pim * fre;
        Pre = nre;
        Pim = nim;
        z_cur = zn;
    }

    // ---- s = NS-1: contribution only (f[127] is never consumed)
    {
        const int s = NSs - 1;
        float xre = xp[(size_t)s * XS];
        float xim = xp[(size_t)s * XS + NCH * INNER];
        float ar  = xp[(size_t)s * XS + 2 * NCH * INNER];
        float alpha = 1.0f - __expf(-ar);
        float amp = ampc / z_cur;
        float k   = alpha * amp;
        float cre = k * Pre;
        float cim = k * Pim;
        accre = fmaf(xre, cre, fmaf(-xim, cim, accre));
        accim = fmaf(xre, cim, fmaf( xim, cre, accim));
    }

    // PLANAR complex output: real plane, then imag plane
    out[tid]        = accre;
    out[NOUT + tid] = accim;
}

extern "C" void kernel_launch(void* const* d_in, const int* in_sizes, int n_in,
                              void* d_out, int out_size, void* d_ws, size_t ws_size,
                              hipStream_t stream) {
    const float* x  = (const float*)d_in[0];
    const float* zv = (const float*)d_in[1];
    const float* fc = (const float*)d_in[2];
    float* out = (float*)d_out;

    render_kernel<<<NOUT / 256, 256, 0, stream>>>(x, zv, fc, out);
}